// Round 2
// baseline (305.739 us; speedup 1.0000x reference)
//
#include <hip/hip_runtime.h>

// SoftmaxCascade: B=8192 rows, E=4681 nodes, 8-ary implicit heap
// (children of p are 8p+1..8p+8). out[0]=1; out[i]=exp(x[i]+D[(i-1)>>3])
// where D[p]=adj[p]+x[p]+D[parent(p)], adj[g]=-m-log(sum exp) over group g.
//
// R1 analysis: latency-bound (2.35 TB/s, VALU 22%). Fixes:
//  - async global->LDS staging (global_load_lds width 16) for deep MLP
//  - contiguous LDS, all bulk reads lane-stride-1 (zero bank conflicts)
//  - group stats via octet shfl_xor in one parallel pass (no level serialism)

constexpr int E  = 4681;
constexpr int NG = 585;   // internal nodes / sibling groups

__global__ __launch_bounds__(256) void cascade_kernel(const float* __restrict__ in,
                                                      float* __restrict__ out) {
    __shared__ float xs[E];    // row, natural order (contiguous: required by global_load_lds)
    __shared__ float dj[NG];   // adj[g] -> D[g] in place
    const int tid  = threadIdx.x;
    const int lane = tid & 63;
    const long long rowbase = (long long)blockIdx.x * (long long)E;
    const float* __restrict__ rin  = in  + rowbase;
    float* __restrict__       rout = out + rowbase;

    // ---- stage global -> LDS, async 16B/lane ----
    // rowbase mod 4 == b mod 4 (E==1 mod 4); peel s elems so vector body is 16B-aligned.
    const int s   = (int)((4 - (rowbase & 3)) & 3);
    const int nv4 = (E - s) >> 2;              // 1169 or 1170 float4 chunks
    const float* vbase = rin + s;              // 16B-aligned
    const int wbase = tid - lane;              // wave-uniform
    #pragma unroll
    for (int u = 0; u < 5; ++u) {
        const int f = u * 256 + wbase;         // tile start (float4 units), wave-uniform
        if (f < nv4) {
            const int idx = f + lane;
            if (idx < nv4) {
                __builtin_amdgcn_global_load_lds(
                    (const __attribute__((address_space(1))) void*)(vbase + 4 * idx),
                    (__attribute__((address_space(3))) void*)(&xs[s + 4 * f]),
                    16, 0, 0);
            }
        }
    }
    // head (s<=3) + tail (<=3) scalars
    if (tid < s) xs[tid] = rin[tid];
    const int t0 = s + 4 * nv4;
    if (tid < E - t0) xs[t0 + tid] = rin[t0 + tid];
    __syncthreads();   // drains vmcnt for global_load_lds

    // ---- pass A: per-group max/lse via octet shuffles ----
    // thread j handles node j+1; group g=j>>3 occupies 8 consecutive lanes.
    for (int j = tid; j < E - 1; j += 256) {   // E-1 = 4680 = 585*8: octets stay complete
        const float v = xs[j + 1];
        float m = v;
        m = fmaxf(m, __shfl_xor(m, 1));
        m = fmaxf(m, __shfl_xor(m, 2));
        m = fmaxf(m, __shfl_xor(m, 4));
        float e = __expf(v - m);
        e += __shfl_xor(e, 1);
        e += __shfl_xor(e, 2);
        e += __shfl_xor(e, 4);
        if ((j & 7) == 0) dj[j >> 3] = -m - __logf(e);
    }
    __syncthreads();

    // ---- cascade D[p] = adj[p] + x[p] + D[parent], in place (3 tiny levels) ----
    if (tid >= 1 && tid <= 8) dj[tid] += xs[tid] + dj[0];          // level 1 (D[0]=adj[0], no-op)
    __syncthreads();
    if (tid >= 9 && tid < 73) dj[tid] += xs[tid] + dj[(tid - 1) >> 3];
    __syncthreads();
    for (int p = 73 + tid; p < NG; p += 256) dj[p] += xs[p] + dj[(p - 1) >> 3];
    __syncthreads();

    // ---- pass B: out[i] = exp(x[i] + D[(i-1)>>3]) ----
    // xs read lane-stride-1 (free); dj read is an 8-lane broadcast (free);
    // stores coalesced 4B/lane.
    for (int j = tid; j < E - 1; j += 256) {
        rout[j + 1] = __expf(xs[j + 1] + dj[j >> 3]);
    }
    if (tid == 0) rout[0] = 1.0f;
}

extern "C" void kernel_launch(void* const* d_in, const int* in_sizes, int n_in,
                              void* d_out, int out_size, void* d_ws, size_t ws_size,
                              hipStream_t stream) {
    const float* in = (const float*)d_in[0];   // [B, E] float32
    float* out = (float*)d_out;                // [B, E] float32
    const int B = in_sizes[0] / E;             // 8192
    cascade_kernel<<<B, 256, 0, stream>>>(in, out);
}

// Round 3
// 298.616 us; speedup vs baseline: 1.0239x; 1.0239x over previous
//
#include <hip/hip_runtime.h>

// SoftmaxCascade: B=8192 rows, E=4681 nodes, 8-ary implicit heap
// (children of p = 8p+1..8p+8). out[0]=1; out[i]=exp(x[i]+D[(i-1)>>3]) where
// D[g]=adj[g]+x[g]+D[parent(g)], D[0]=adj[0], adj[g]=-m-log(sum exp(x_c-m)).
//
// R2 post-mortem: LDS-pipe/VALU bound (6 bpermutes/elt + LDS round trips,
// 5 barriers), HBM at 28%. R3: register-resident octets -- one thread owns
// group g, loads x[8g..8g+8] into regs via alignment-specialized float4
// windows, computes stats in-register, LDS only for per-group scalars
// (adj/xnode/D ~7KB), 2 barriers, alignment-specialized vector stores.

constexpr int E  = 4681;
constexpr int NG = 585;                 // internal nodes / sibling groups

__device__ __forceinline__ int xslot(int p) { return p + (p >> 3); } // pad-9 slot
constexpr int XN = 658;                 // xslot(584)=657

// Load w[0..8] = x[8g .. 8g+8]. R = (rowbase & 3): rin+8g is R floats past
// a 16B boundary, so load 3 aligned float4 covering [8g-R .. 8g-R+11] and
// select. g==584 (last group, row tail) takes the scalar path to avoid OOB.
template<int R>
__device__ __forceinline__ void loadw(const float* __restrict__ rin, int g, float w[9]) {
    if (g == 584) {
        #pragma unroll
        for (int k = 0; k < 9; ++k) w[k] = rin[4672 + k];
        return;
    }
    if (R == 0) {
        const float4 A = *(const float4*)(rin + 8 * g);
        const float4 B = *(const float4*)(rin + 8 * g + 4);
        w[0] = A.x; w[1] = A.y; w[2] = A.z; w[3] = A.w;
        w[4] = B.x; w[5] = B.y; w[6] = B.z; w[7] = B.w;
        w[8] = rin[8 * g + 8];
    } else {
        const float4 A = *(const float4*)(rin + 8 * g - R);
        const float4 B = *(const float4*)(rin + 8 * g - R + 4);
        const float4 C = *(const float4*)(rin + 8 * g - R + 8);
        const float L[12] = {A.x, A.y, A.z, A.w, B.x, B.y, B.z, B.w, C.x, C.y, C.z, C.w};
        #pragma unroll
        for (int k = 0; k < 9; ++k) w[k] = L[R + k];   // R compile-time: reg selects
    }
}

// Store y[0..7] -> out[8g..8g+7] with natural-alignment segments (block-uniform R).
// g==584 also stores y[8] -> out[4680].
template<int R>
__device__ __forceinline__ void storew(float* __restrict__ rout, int g, const float y[9]) {
    if (g == 584) {
        #pragma unroll
        for (int k = 0; k < 9; ++k) rout[4672 + k] = y[k];
        return;
    }
    float* q = rout + 8 * g;            // float index === R (mod 4)
    if (R == 0) {
        *(float4*)(q)     = make_float4(y[0], y[1], y[2], y[3]);
        *(float4*)(q + 4) = make_float4(y[4], y[5], y[6], y[7]);
    } else if (R == 1) {
        q[0] = y[0];
        *(float2*)(q + 1) = make_float2(y[1], y[2]);
        *(float4*)(q + 3) = make_float4(y[3], y[4], y[5], y[6]);
        q[7] = y[7];
    } else if (R == 2) {
        *(float2*)(q)     = make_float2(y[0], y[1]);
        *(float4*)(q + 2) = make_float4(y[2], y[3], y[4], y[5]);
        *(float2*)(q + 6) = make_float2(y[6], y[7]);
    } else {
        q[0] = y[0];
        *(float4*)(q + 1) = make_float4(y[1], y[2], y[3], y[4]);
        *(float2*)(q + 5) = make_float2(y[5], y[6]);
        q[7] = y[7];
    }
}

__device__ __forceinline__ float group_adj(const float w[9]) {
    float m = w[1];
    #pragma unroll
    for (int k = 2; k < 9; ++k) m = fmaxf(m, w[k]);
    float s = 0.0f;
    #pragma unroll
    for (int k = 1; k < 9; ++k) s += __expf(w[k] - m);
    return -m - __logf(s);
}

__device__ __forceinline__ float walkD(int g, const float* adj, const float* xn) {
    float D = adj[g];
    int q = g;
    #pragma unroll
    for (int it = 0; it < 3; ++it) {     // depth <= 3 ancestor hops for g<=584
        if (q > 0) {
            D += xn[xslot(q)];
            q = (q - 1) >> 3;
            D += adj[q];
        }
    }
    return D;
}

template<int R>
__device__ __forceinline__ void row_body(const float* __restrict__ rin,
                                         float* __restrict__ rout,
                                         float* adj, float* dj, float* xn, int tid) {
    const int g0 = tid, g1 = tid + 256, g2 = tid + 512;   // g0,g1 always valid
    const bool h2 = (g2 < NG);                             // tid < 73
    float w0[9], w1[9], w2[9];
    loadw<R>(rin, g0, w0);                                 // all loads issued up front
    loadw<R>(rin, g1, w1);
    if (h2) loadw<R>(rin, g2, w2);

    adj[g0] = group_adj(w0);
    adj[g1] = group_adj(w1);
    if (h2) adj[g2] = group_adj(w2);

    // stage x of internal nodes 1..584 (they live in windows g<=73)
    if (g0 <= 73) {
        #pragma unroll
        for (int k = 0; k < 8; ++k) {
            const int node = 8 * g0 + k;
            if (node >= 1 && node <= 584) xn[xslot(node)] = w0[k];  // pad-9: conflict-free
        }
    }
    __syncthreads();

    const float D0 = walkD(g0, adj, xn);
    const float D1 = walkD(g1, adj, xn);
    const float D2 = h2 ? walkD(g2, adj, xn) : 0.0f;
    dj[g0] = D0; dj[g1] = D1;
    if (h2) dj[g2] = D2;
    __syncthreads();

    float y[9];
    {
        const float Dp = (g0 > 0) ? dj[g0 - 1] : 0.0f;     // out[8g] belongs to group g-1
        y[0] = (g0 == 0) ? 1.0f : __expf(w0[0] + Dp);      // root: p=1
        #pragma unroll
        for (int k = 1; k < 8; ++k) y[k] = __expf(w0[k] + D0);
        y[8] = 0.0f;
        storew<R>(rout, g0, y);
    }
    {
        const float Dp = dj[g1 - 1];
        y[0] = __expf(w1[0] + Dp);
        #pragma unroll
        for (int k = 1; k < 8; ++k) y[k] = __expf(w1[k] + D1);
        y[8] = 0.0f;
        storew<R>(rout, g1, y);
    }
    if (h2) {
        const float Dp = dj[g2 - 1];
        y[0] = __expf(w2[0] + Dp);
        #pragma unroll
        for (int k = 1; k < 8; ++k) y[k] = __expf(w2[k] + D2);
        y[8] = __expf(w2[8] + D2);                         // node 4680 (only g==584 stores it)
        storew<R>(rout, g2, y);
    }
}

__global__ __launch_bounds__(256, 4) void cascade_kernel(const float* __restrict__ in,
                                                         float* __restrict__ out) {
    __shared__ float adj[NG];
    __shared__ float dj[NG];
    __shared__ float xn[XN];
    const int tid = threadIdx.x;
    const long long rowbase = (long long)blockIdx.x * (long long)E;
    const float* rin = in + rowbase;
    float* rout = out + rowbase;
    switch ((int)(rowbase & 3)) {        // == blockIdx.x & 3 (E odd): block-uniform
        case 0: row_body<0>(rin, rout, adj, dj, xn, tid); break;
        case 1: row_body<1>(rin, rout, adj, dj, xn, tid); break;
        case 2: row_body<2>(rin, rout, adj, dj, xn, tid); break;
        case 3: row_body<3>(rin, rout, adj, dj, xn, tid); break;
    }
}

extern "C" void kernel_launch(void* const* d_in, const int* in_sizes, int n_in,
                              void* d_out, int out_size, void* d_ws, size_t ws_size,
                              hipStream_t stream) {
    const float* in = (const float*)d_in[0];   // [B, E] float32
    float* out = (float*)d_out;                // [B, E] float32
    const int B = in_sizes[0] / E;             // 8192
    cascade_kernel<<<B, 256, 0, stream>>>(in, out);
}